// Round 8
// baseline (165.588 us; speedup 1.0000x reference)
//
#include <hip/hip_runtime.h>
#include <math.h>

// ---------------------------------------------------------------------------
// HyperbolicInfoNCE on MI355X — Round 8: single fused kernel.
//   inner = z1 @ diag(-1,1,...,1) @ z2^T  (8192x8192, K=129)
//   sims  = -acosh(max(-inner, 1+1e-6)) / 0.07
//   loss  = mean_b( 0.5*ln(sum_k e^{sims[b,k]}) + 0.5*ln(sum_k e^{sims[k,b]})
//                   - sims[b,b] )
//
// Journal lessons baked in:
//   R5: NO device-scope fences in per-block hot path (L2 wb/inv storm).
//   R5/R7: compiler refuses deep explicit register pipelines — caps at ~128
//          arch VGPRs and SPILLS (R7: 126MB scratch traffic, 58.8->108us).
//          Keep R6's simple loop; let the compiler schedule.
//   R6: ownership restructure (wave = 64 rows x 4 col-tiles, consecutive
//       blocks share B-chunk) fixed the latency wall: 147->58.8us.
//   R7: fence-free atomic finalize protocol verified correct.
// This round: fuse fp32->bf16 conversion into the GEMM (direct z1/z2 reads,
// in-register (__bf16) casts -> v_cvt_pk_bf16_f32 on gfx950), K=129 as
// 4 full k-tiles + 1 rank-1 MFMA batch. One kernel + one memset node.
// ---------------------------------------------------------------------------

#define BDIM   8192
#define K129   129
#define CTILES 4              // 64-col tiles per wave
#define NBLK   1024

typedef __bf16  bf16x8 __attribute__((ext_vector_type(8)));
typedef float   f32x4  __attribute__((ext_vector_type(4)));
typedef float   f32x4u __attribute__((ext_vector_type(4), aligned(4)));  // rows stride 129 -> 4B align only

// ws layout (bytes): rs | cp[4 replicas] | dg | cnt   (zeroed by one memset)
#define OFF_RS   0u
#define OFF_CP   (BDIM * 4u)
#define OFF_DG   (OFF_CP + 4u * BDIM * 4u)
#define OFF_CNT  (OFF_DG + BDIM * 4u)
#define ZERO_BYTES (OFF_CNT + 64u)

// ---- hardware transcendentals (v_sqrt_f32 / v_log_f32 / v_exp_f32) ----
__device__ __forceinline__ float fast_sqrt(float x) {
#if __has_builtin(__builtin_amdgcn_sqrtf)
    return __builtin_amdgcn_sqrtf(x);
#else
    return sqrtf(x);
#endif
}
__device__ __forceinline__ float fast_log2(float x) {
#if __has_builtin(__builtin_amdgcn_logf)
    return __builtin_amdgcn_logf(x);       // log base 2
#else
    return __log2f(x);
#endif
}
__device__ __forceinline__ float fast_exp2(float x) {
#if __has_builtin(__builtin_amdgcn_exp2f)
    return __builtin_amdgcn_exp2f(x);      // 2^x
#else
    extern "C" __device__ float __ocml_native_exp2_f32(float);
    return __ocml_native_exp2_f32(x);
#endif
}

// 8 fp32 -> bf16x8 fragment (RNE; lowers to v_cvt_pk_bf16_f32 on gfx950)
__device__ __forceinline__ bf16x8 cvt8(f32x4u a, f32x4u b) {
    bf16x8 r;
    r[0] = (__bf16)a[0]; r[1] = (__bf16)a[1];
    r[2] = (__bf16)a[2]; r[3] = (__bf16)a[3];
    r[4] = (__bf16)b[0]; r[5] = (__bf16)b[1];
    r[6] = (__bf16)b[2]; r[7] = (__bf16)b[3];
    return r;
}

// ---------------------------------------------------------------------------
// Fused kernel: strip-GEMM straight from fp32 inputs + acosh/exp epilogue +
// last-block finalize.
//   grid = 1024: bid = chunk*64 + strip  (consecutive blocks share B-chunk)
//   block: rows [strip*128,+128) x cols [chunk*512,+512); 4 waves 2x2;
//   wave: 64 rows x 4 col-tiles of 64x64 (4x4 MFMA 16x16x32 each).
//   fragment layouts (guide-verified, m89/m91):
//     A/B: elem [m=lane&15][k=(lane>>4)*8 + j]
//     C/D: elem [row=(lane>>4)*4 + reg][col=lane&15]
//   K=129: kt=0..3 full 32-wide tiles (k<128); 5th batch carries only k=128
//   (elem0 of quad 0), rest zero. Lorentz metric = negate A elem0 (kt=0,quad=0).
// ---------------------------------------------------------------------------
__global__ __launch_bounds__(256, 2) void gemm_fused_kernel(
    const float* __restrict__ z1, const float* __restrict__ z2,
    float* __restrict__ row_sum, float* __restrict__ col_part,
    float* __restrict__ diag, unsigned int* __restrict__ cnt,
    float* __restrict__ out)
{
    const int t    = threadIdx.x;
    const int lane = t & 63;
    const int wave = t >> 6;
    const int quad = lane >> 4;
    const int l16  = lane & 15;

    const int strip = blockIdx.x & 63;
    const int chunk = blockIdx.x >> 6;
    const int wr      = (wave >> 1) * 64;
    const int rowBase = strip * 128 + wr;
    const int colWave = chunk * 512 + (wave & 1) * 256;

    const float* Az = z1 + (rowBase + l16) * K129 + quad * 8;
    float* colRep = col_part + (strip & 3) * BDIM;

    bf16x8 zfrag;
    #pragma unroll
    for (int e = 0; e < 8; ++e) zfrag[e] = (__bf16)0.f;

    float rowp[4][4] = {};

    for (int ct = 0; ct < CTILES; ++ct) {
        const int colBase = colWave + ct * 64;
        const float* Bz = z2 + (colBase + l16) * K129 + quad * 8;

        f32x4 acc[4][4] = {};

        // ---- kt = 0..3 : full 32-wide K-tiles ----
        #pragma unroll
        for (int kt = 0; kt < 4; ++kt) {
            bf16x8 af[4], bfr[4];
            #pragma unroll
            for (int i = 0; i < 4; ++i) {
                const float* pa = Az + i * 16 * K129 + kt * 32;
                f32x4u a0 = *(const f32x4u*)pa;
                f32x4u a1 = *(const f32x4u*)(pa + 4);
                if (kt == 0 && quad == 0) a0[0] = -a0[0];   // Lorentz metric
                af[i] = cvt8(a0, a1);
                const float* pb = Bz + i * 16 * K129 + kt * 32;
                bfr[i] = cvt8(*(const f32x4u*)pb, *(const f32x4u*)(pb + 4));
            }
            #pragma unroll
            for (int i = 0; i < 4; ++i)
                #pragma unroll
                for (int j = 0; j < 4; ++j)
                    acc[i][j] = __builtin_amdgcn_mfma_f32_16x16x32_bf16(
                                    af[i], bfr[j], acc[i][j], 0, 0, 0);
        }

        // ---- 5th batch: lone k=128 (rank-1 update via MFMA) ----
        {
            bf16x8 af[4], bfr[4];
            #pragma unroll
            for (int i = 0; i < 4; ++i) {
                float va = z1[(rowBase + i * 16 + l16) * K129 + 128];
                float vb = z2[(colBase + i * 16 + l16) * K129 + 128];
                af[i] = zfrag;
                bfr[i] = zfrag;
                af[i][0]  = (quad == 0) ? (__bf16)va : (__bf16)0.f;
                bfr[i][0] = (quad == 0) ? (__bf16)vb : (__bf16)0.f;
            }
            #pragma unroll
            for (int i = 0; i < 4; ++i)
                #pragma unroll
                for (int j = 0; j < 4; ++j)
                    acc[i][j] = __builtin_amdgcn_mfma_f32_16x16x32_bf16(
                                    af[i], bfr[j], acc[i][j], 0, 0, 0);
        }

        // ---- fused epilogue for this 64x64 tile ----
        // u = x + sqrt(x^2-1), x = max(-inner, 1+1e-6)
        // exp(sims) = exp2(-14.2857142857 * log2(u))
        // sims      = -(ln2/0.07) * log2(u)
        const bool diagTile = (colBase == rowBase);
        float colp[4] = {0.f, 0.f, 0.f, 0.f};

        #pragma unroll
        for (int i = 0; i < 4; ++i) {
            #pragma unroll
            for (int j = 0; j < 4; ++j) {
                #pragma unroll
                for (int reg = 0; reg < 4; ++reg) {
                    float inner = acc[i][j][reg];
                    float x = fmaxf(-inner, 1.000001f);
                    float sq = fast_sqrt(__builtin_fmaf(x, x, -1.0f));
                    float l2u = fast_log2(x + sq);
                    float e = fast_exp2(-14.285714285714286f * l2u);
                    rowp[i][reg] += e;
                    colp[j]      += e;
                    if (diagTile && i == j && (quad * 4 + reg) == l16) {
                        int R = rowBase + i * 16 + quad * 4 + reg;
                        atomicAdd(&diag[R], -9.902102579427789f * l2u);
                    }
                }
            }
        }
        // col sums: reduce across quads, one atomic per col
        #pragma unroll
        for (int j = 0; j < 4; ++j) {
            float v = colp[j];
            v += __shfl_xor(v, 16);
            v += __shfl_xor(v, 32);
            if (quad == 0)
                atomicAdd(&colRep[colBase + j * 16 + l16], v);
        }
    }

    // row sums (accumulated over all 4 col-tiles): reduce across quad lanes
    #pragma unroll
    for (int i = 0; i < 4; ++i) {
        #pragma unroll
        for (int reg = 0; reg < 4; ++reg) {
            float v = rowp[i][reg];
            v += __shfl_xor(v, 1);
            v += __shfl_xor(v, 2);
            v += __shfl_xor(v, 4);
            v += __shfl_xor(v, 8);
            if (l16 == 0)
                atomicAdd(&row_sum[rowBase + i * 16 + quad * 4 + reg], v);
        }
    }

    // ---- fused finalize: atomic-only protocol, NO fences (R7-verified) ----
    __builtin_amdgcn_s_waitcnt(0);
    __shared__ unsigned int lastFlag;
    __shared__ float part[4];
    __syncthreads();
    if (t == 0) {
        unsigned int old = atomicAdd(cnt, 1u);
        lastFlag = (old == NBLK - 1u) ? 1u : 0u;
    }
    __syncthreads();
    if (lastFlag) {
        const float LN2_HALF = 0.34657359027997264f;  // 0.5 * ln2
        float a = 0.f;
        for (int b = t; b < BDIM; b += 256) {
            float r  = __hip_atomic_load(&row_sum[b], __ATOMIC_RELAXED,
                                         __HIP_MEMORY_SCOPE_AGENT);
            float c0 = __hip_atomic_load(&col_part[b], __ATOMIC_RELAXED,
                                         __HIP_MEMORY_SCOPE_AGENT);
            float c1 = __hip_atomic_load(&col_part[b + BDIM], __ATOMIC_RELAXED,
                                         __HIP_MEMORY_SCOPE_AGENT);
            float c2 = __hip_atomic_load(&col_part[b + 2 * BDIM], __ATOMIC_RELAXED,
                                         __HIP_MEMORY_SCOPE_AGENT);
            float c3 = __hip_atomic_load(&col_part[b + 3 * BDIM], __ATOMIC_RELAXED,
                                         __HIP_MEMORY_SCOPE_AGENT);
            float d  = __hip_atomic_load(&diag[b], __ATOMIC_RELAXED,
                                         __HIP_MEMORY_SCOPE_AGENT);
            a += LN2_HALF * (fast_log2(r) + fast_log2(c0 + c1 + c2 + c3)) - d;
        }
        #pragma unroll
        for (int m = 1; m < 64; m <<= 1) a += __shfl_xor(a, m);
        if (lane == 0) part[wave] = a;
        __syncthreads();
        if (t == 0)
            out[0] = (part[0] + part[1] + part[2] + part[3])
                     * (1.0f / (float)BDIM);
    }
}

// ---------------------------------------------------------------------------
extern "C" void kernel_launch(void* const* d_in, const int* in_sizes, int n_in,
                              void* d_out, int out_size, void* d_ws, size_t ws_size,
                              hipStream_t stream)
{
    const float* z1 = (const float*)d_in[0];
    const float* z2 = (const float*)d_in[1];
    float* out = (float*)d_out;

    char* ws = (char*)d_ws;
    float* row_sum     = (float*)(ws + OFF_RS);
    float* col_part    = (float*)(ws + OFF_CP);
    float* diag        = (float*)(ws + OFF_DG);
    unsigned int* cnt  = (unsigned int*)(ws + OFF_CNT);

    // zero accumulators + counter (ws poisoned 0xAA before every call)
    hipMemsetAsync(ws, 0, ZERO_BYTES, stream);

    gemm_fused_kernel<<<NBLK, 256, 0, stream>>>(
        z1, z2, row_sum, col_part, diag, cnt, out);
}